// Round 2
// baseline (64.503 us; speedup 1.0000x reference)
//
#include <hip/hip_runtime.h>

// Problem constants (from reference)
#define BB 16
#define NN 48
#define KK 7
#define PADP 3
#define KCUBE (KK * KK * KK)  // 343

// One block per (b, i) output window. Threads 0..342 each compute one window
// cell by scanning the <=48 acid points and <=47 interpolated midpoints for a
// coordinate match. Sequential ascending-j scans reproduce the reference's
// scatter ordering exactly (acids first, inters overwrite, later j wins).
__global__ __launch_bounds__(384) void LatticeSnake_kernel(
    const float* __restrict__ acids,  // (B, N) f32
    const int* __restrict__ mask,     // (B, N) bool -> harness-converted int32
    const int* __restrict__ idx,      // (B, N, 3) i32
    float* __restrict__ out)          // (B, N, K, K, K, 1) f32
{
    const int blk = blockIdx.x;      // b * N + i
    const int b = blk / NN;
    const int i = blk % NN;
    const int t = threadIdx.x;

    __shared__ int s_idx2[NN][3];
    __shared__ float s_ac[NN];
    __shared__ int s_mk[NN];
    __shared__ int s_ii[NN - 1][3];
    __shared__ float s_iv[NN - 1];

    if (t < NN) {
        s_ac[t] = acids[b * NN + t];
        s_mk[t] = mask[b * NN + t];
#pragma unroll
        for (int d = 0; d < 3; ++d)
            s_idx2[t][d] = 2 * (idx[(b * NN + t) * 3 + d] + (NN - 1));
    }
    __syncthreads();
    if (t < NN - 1) {
#pragma unroll
        for (int d = 0; d < 3; ++d)
            s_ii[t][d] = (s_idx2[t][d] + s_idx2[t + 1][d]) >> 1;
        s_iv[t] = s_ac[t] + s_ac[t + 1] + 1.0f;
    }
    __syncthreads();

    if (t < KCUBE) {
        const int oz = t % KK;
        const int oy = (t / KK) % KK;
        const int ox = t / (KK * KK);
        const int qx = s_idx2[i][0] + ox - PADP;
        const int qy = s_idx2[i][1] + oy - PADP;
        const int qz = s_idx2[i][2] + oz - PADP;

        float v = 0.0f;
        // Acid scatter pass (later j overwrites earlier on duplicate coords)
        for (int j = 0; j < NN; ++j) {
            if (s_mk[j] && s_idx2[j][0] == qx && s_idx2[j][1] == qy &&
                s_idx2[j][2] == qz)
                v = s_ac[j];
        }
        // Interpolated-midpoint scatter pass (applied after acids -> wins)
        for (int j = 0; j < NN - 1; ++j) {
            if (s_mk[j + 1] && s_ii[j][0] == qx && s_ii[j][1] == qy &&
                s_ii[j][2] == qz)
                v = s_iv[j];
        }
        if (!s_mk[i]) v = 0.0f;
        out[blk * KCUBE + t] = v;
    }
}

extern "C" void kernel_launch(void* const* d_in, const int* in_sizes, int n_in,
                              void* d_out, int out_size, void* d_ws, size_t ws_size,
                              hipStream_t stream) {
    const float* acids = (const float*)d_in[0];
    const int* mask = (const int*)d_in[1];
    const int* idx = (const int*)d_in[2];
    float* out = (float*)d_out;

    dim3 grid(BB * NN);   // 768 blocks
    dim3 block(384);      // 343 active window cells, padded to 6 waves
    LatticeSnake_kernel<<<grid, block, 0, stream>>>(acids, mask, idx, out);
}

// Round 4
// 57.563 us; speedup vs baseline: 1.1206x; 1.1206x over previous
//
#include <hip/hip_runtime.h>

// Problem constants (from reference)
#define BB 16
#define NN 48
#define KK 7
#define PADP 3
#define KCUBE (KK * KK * KK)  // 343

// One block per (b, i) output window. Inverted strategy vs the scan version:
// each of the <=95 candidate points (48 acids + 47 midpoints) bounds-checks
// itself against the 7^3 window and scatters a priority key into LDS via
// atomicMax. Key = (pass<<6 | j) + 1 is monotone in the reference's scatter
// order (acids first, inters overwrite, later j wins), so atomicMax resolves
// duplicate-coordinate collisions with exactly the reference semantics.
__global__ __launch_bounds__(384) void LatticeSnake_kernel(
    const float* __restrict__ acids,  // (B, N) f32
    const int* __restrict__ mask,     // (B, N) bool -> harness int32
    const int* __restrict__ idx,      // (B, N, 3) i32
    float* __restrict__ out)          // (B, N, K, K, K, 1) f32
{
    const int blk = blockIdx.x;      // b * N + i
    const int b = blk / NN;
    const int i = blk % NN;
    const int t = threadIdx.x;

    __shared__ int s_idx2[NN][3];
    __shared__ float s_ac[NN];
    __shared__ int s_mk[NN];
    __shared__ int s_ii[NN - 1][3];
    __shared__ float s_iv[NN - 1];
    __shared__ int s_win[KCUBE];     // winner key per window cell (0 = empty)

    if (t < NN) {
        s_ac[t] = acids[b * NN + t];
        s_mk[t] = mask[b * NN + t];
#pragma unroll
        for (int d = 0; d < 3; ++d)
            s_idx2[t][d] = 2 * (idx[(b * NN + t) * 3 + d] + (NN - 1));
    }
    if (t < KCUBE) s_win[t] = 0;
    __syncthreads();

    if (t < NN - 1) {
#pragma unroll
        for (int d = 0; d < 3; ++d)
            s_ii[t][d] = (s_idx2[t][d] + s_idx2[t + 1][d]) >> 1;
        s_iv[t] = s_ac[t] + s_ac[t + 1] + 1.0f;
    }
    __syncthreads();

    // Scatter pass: threads 0..47 = acids, threads 48..94 = midpoints.
    // Window (padded-lattice) span is [idx2[i], idx2[i]+K); a point at
    // padded coord p+PAD lands at offset o = p - idx2[i] + PAD in [0, K).
    const int bx = s_idx2[i][0], by = s_idx2[i][1], bz = s_idx2[i][2];
    if (t < NN) {                       // acid pass, priority = j+1
        if (s_mk[t]) {
            const int ox = s_idx2[t][0] - bx + PADP;
            const int oy = s_idx2[t][1] - by + PADP;
            const int oz = s_idx2[t][2] - bz + PADP;
            if (((unsigned)ox < KK) & ((unsigned)oy < KK) & ((unsigned)oz < KK))
                atomicMax(&s_win[(ox * KK + oy) * KK + oz], t + 1);
        }
    } else if (t < 2 * NN - 1) {        // inter pass, priority = 64+j+1
        const int j = t - NN;
        if (s_mk[j + 1]) {
            const int ox = s_ii[j][0] - bx + PADP;
            const int oy = s_ii[j][1] - by + PADP;
            const int oz = s_ii[j][2] - bz + PADP;
            if (((unsigned)ox < KK) & ((unsigned)oy < KK) & ((unsigned)oz < KK))
                atomicMax(&s_win[(ox * KK + oy) * KK + oz], 64 + j + 1);
        }
    }
    __syncthreads();

    // Resolve winners and write the window out (contiguous, coalesced).
    if (t < KCUBE) {
        float v = 0.0f;
        const int k = s_win[t];
        if (k > 0 && s_mk[i]) {
            const int key = k - 1;
            v = (key >= 64) ? s_iv[key - 64] : s_ac[key];
        }
        out[blk * KCUBE + t] = v;
    }
}

extern "C" void kernel_launch(void* const* d_in, const int* in_sizes, int n_in,
                              void* d_out, int out_size, void* d_ws, size_t ws_size,
                              hipStream_t stream) {
    const float* acids = (const float*)d_in[0];
    const int* mask = (const int*)d_in[1];
    const int* idx = (const int*)d_in[2];
    float* out = (float*)d_out;

    dim3 grid(BB * NN);   // 768 blocks
    dim3 block(384);      // 343 active window cells, padded to 6 waves
    LatticeSnake_kernel<<<grid, block, 0, stream>>>(acids, mask, idx, out);
}

// Round 5
// 57.478 us; speedup vs baseline: 1.1222x; 1.0015x over previous
//
#include <hip/hip_runtime.h>

// Problem constants (from reference)
#define BB 16
#define NN 48
#define KK 7
#define PADP 3
#define KCUBE (KK * KK * KK)  // 343

// One 64-lane wave per (b, i) output window. Each of the <=95 candidate
// points (48 acids + 47 midpoints) bounds-checks itself against the 7^3
// window and scatters a priority key into LDS via atomicMax.
// Key = (pass<<6 | j) + 1 is monotone in the reference's scatter order
// (acids first, inters overwrite, later j wins), so atomicMax resolves
// duplicate-coordinate collisions with exactly the reference semantics.
// Resolve is a 6-iteration strided loop over the 343 cells (coalesced
// output writes). Single-wave blocks make the barriers nearly free.
__global__ __launch_bounds__(64) void LatticeSnake_kernel(
    const float* __restrict__ acids,  // (B, N) f32
    const int* __restrict__ mask,     // (B, N) bool -> harness int32
    const int* __restrict__ idx,      // (B, N, 3) i32
    float* __restrict__ out)          // (B, N, K, K, K, 1) f32
{
    const int blk = blockIdx.x;      // b * N + i
    const int b = blk / NN;
    const int i = blk % NN;
    const int t = threadIdx.x;       // 0..63

    __shared__ int s_idx2[NN][3];
    __shared__ float s_ac[NN];
    __shared__ int s_mk[NN];
    __shared__ int s_ii[NN - 1][3];
    __shared__ float s_iv[NN - 1];
    __shared__ int s_win[KCUBE];     // winner key per window cell (0 = empty)

    if (t < NN) {
        s_ac[t] = acids[b * NN + t];
        s_mk[t] = mask[b * NN + t];
#pragma unroll
        for (int d = 0; d < 3; ++d)
            s_idx2[t][d] = 2 * (idx[(b * NN + t) * 3 + d] + (NN - 1));
    }
#pragma unroll
    for (int c = t; c < KCUBE; c += 64) s_win[c] = 0;
    __syncthreads();

    if (t < NN - 1) {
#pragma unroll
        for (int d = 0; d < 3; ++d)
            s_ii[t][d] = (s_idx2[t][d] + s_idx2[t + 1][d]) >> 1;
        s_iv[t] = s_ac[t] + s_ac[t + 1] + 1.0f;
    }
    __syncthreads();

    // Scatter: window (padded-lattice) span is [idx2[i], idx2[i]+K); a point
    // at padded coord p+PAD lands at offset o = p - idx2[i] + PAD in [0, K).
    const int bx = s_idx2[i][0], by = s_idx2[i][1], bz = s_idx2[i][2];
    if (t < NN && s_mk[t]) {            // acid pass, priority = j+1
        const int ox = s_idx2[t][0] - bx + PADP;
        const int oy = s_idx2[t][1] - by + PADP;
        const int oz = s_idx2[t][2] - bz + PADP;
        if (((unsigned)ox < KK) & ((unsigned)oy < KK) & ((unsigned)oz < KK))
            atomicMax(&s_win[(ox * KK + oy) * KK + oz], t + 1);
    }
    if (t < NN - 1 && s_mk[t + 1]) {    // inter pass, priority = 64+j+1
        const int ox = s_ii[t][0] - bx + PADP;
        const int oy = s_ii[t][1] - by + PADP;
        const int oz = s_ii[t][2] - bz + PADP;
        if (((unsigned)ox < KK) & ((unsigned)oy < KK) & ((unsigned)oz < KK))
            atomicMax(&s_win[(ox * KK + oy) * KK + oz], 64 + t + 1);
    }
    __syncthreads();

    // Resolve winners and write the window out (coalesced per iteration).
    const int base = blk * KCUBE;
    const int mk_i = s_mk[i];
#pragma unroll
    for (int c = t; c < KCUBE; c += 64) {
        float v = 0.0f;
        const int k = s_win[c];
        if (k > 0 && mk_i) {
            const int key = k - 1;
            v = (key >= 64) ? s_iv[key - 64] : s_ac[key];
        }
        out[base + c] = v;
    }
}

extern "C" void kernel_launch(void* const* d_in, const int* in_sizes, int n_in,
                              void* d_out, int out_size, void* d_ws, size_t ws_size,
                              hipStream_t stream) {
    const float* acids = (const float*)d_in[0];
    const int* mask = (const int*)d_in[1];
    const int* idx = (const int*)d_in[2];
    float* out = (float*)d_out;

    dim3 grid(BB * NN);   // 768 blocks, 1 wave each
    dim3 block(64);
    LatticeSnake_kernel<<<grid, block, 0, stream>>>(acids, mask, idx, out);
}